// Round 1
// baseline (212.794 us; speedup 1.0000x reference)
//
#include <hip/hip_runtime.h>
#include <hip/hip_bf16.h>

// Shapes: B=512, BAG=32, H=1024, C=53.  EPS=1e-8, scale=sqrt(1024)=32.
// Out: bag_out (512*53=27136) f32, then cl_loss scalar -> 27137 floats.

typedef __bf16 bf16x8 __attribute__((ext_vector_type(8)));
typedef __bf16 bf16x4 __attribute__((ext_vector_type(4)));
typedef float  f32x4  __attribute__((ext_vector_type(4)));

__device__ inline float wsum(float v) {
    #pragma unroll
    for (int off = 32; off > 0; off >>= 1) v += __shfl_xor(v, off, 64);
    return v;
}

__device__ inline void gll16(const void* g, void* l) {
    __builtin_amdgcn_global_load_lds((const __attribute__((address_space(1))) void*)g,
                                     (__attribute__((address_space(3))) void*)l, 16, 0, 0);
}

__device__ inline f32x4 ntld(const float* p) {
    return __builtin_nontemporal_load((const f32x4*)p);
}

// ---- ka: streaming pass (1 row/wave, NT input loads) + folded k0 ----
__global__ __launch_bounds__(256) void ka(
    const float* __restrict__ sent, const float* __restrict__ aug,
    const float* __restrict__ rel_table, const int* __restrict__ labels,
    __bf16* __restrict__ repb, float* __restrict__ nr, float* __restrict__ pos_sim,
    float* __restrict__ scoreg,
    const float* __restrict__ clsw, __bf16* __restrict__ cwb,
    float* __restrict__ nbsq, float* __restrict__ loss)
{
    const int t = threadIdx.x;
    // folded k0: blocks 0..255 convert cls_w (padded to 64 rows); block 256 zeroes scalars
    if (blockIdx.x < 256) {
        const int i = blockIdx.x * 256 + t;
        cwb[i] = (i < 53 * 1024) ? (__bf16)clsw[i] : (__bf16)0.0f;
    } else if (blockIdx.x == 256) {
        nbsq[t] = 0.0f; nbsq[256 + t] = 0.0f;
        if (t == 0) *loss = 0.0f;
    }

    const int w = t >> 6, lane = t & 63;
    const int row = blockIdx.x * 4 + w;                // 0..16383 (wave-uniform)
    const int b = row >> 5;
    const size_t rbase = (size_t)row * 1024;
    const float* srow = sent + rbase;
    const float* arow = aug + rbase;
    const float* relp = rel_table + (size_t)labels[b] * 1024;

    float P = 0.f, R = 0.f, A = 0.f, D = 0.f;
    #pragma unroll
    for (int i = 0; i < 4; i++) {
        const int h = i * 256 + lane * 4;
        f32x4 v  = ntld(srow + h);                     // nt: read-once, don't pollute L3
        f32x4 a  = ntld(arow + h);
        f32x4 rl = *(const f32x4*)(relp + h);          // reused across bags: keep cached
        P += v.x * rl.x + v.y * rl.y + v.z * rl.z + v.w * rl.w;
        R += v.x * v.x + v.y * v.y + v.z * v.z + v.w * v.w;
        A += a.x * a.x + a.y * a.y + a.z * a.z + a.w * a.w;
        D += v.x * a.x + v.y * a.y + v.z * a.z + v.w * a.w;
        bf16x4 vb = { (__bf16)v.x, (__bf16)v.y, (__bf16)v.z, (__bf16)v.w };
        *(bf16x4*)(repb + rbase + h) = vb;
    }
    #pragma unroll
    for (int off = 32; off > 0; off >>= 1) {
        P += __shfl_xor(P, off, 64);
        R += __shfl_xor(R, off, 64);
        A += __shfl_xor(A, off, 64);
        D += __shfl_xor(D, off, 64);
    }
    if (lane == 0) {
        scoreg[row] = P * (1.0f / 32.0f);              // /sqrt(H)
        float nrv = sqrtf(R), nav = sqrtf(A);
        nr[row] = nrv;
        pos_sim[row] = D / fmaxf(nrv * nav, 1e-8f);
    }
}

// ---- kb: per-b softmax + bag from bf16 repb (L2/L3-hot) ----
__global__ __launch_bounds__(256) void kb(
    const __bf16* __restrict__ repb, const float* __restrict__ scoreg,
    __bf16* __restrict__ bagb, float* __restrict__ nbsq)
{
    __shared__ float alphaS[32];
    const int b = blockIdx.x, t = threadIdx.x;
    if (t < 32) {
        float sj = scoreg[b * 32 + t];
        float m = sj;
        #pragma unroll
        for (int off = 16; off > 0; off >>= 1) m = fmaxf(m, __shfl_xor(m, off, 32));
        float e = __expf(sj - m);
        float sum = e;
        #pragma unroll
        for (int off = 16; off > 0; off >>= 1) sum += __shfl_xor(sum, off, 32);
        alphaS[t] = e / sum;
    }
    __syncthreads();

    f32x4 acc = {};
    const __bf16* base = repb + (size_t)b * 32 * 1024 + t * 4;
    #pragma unroll 8
    for (int jj = 0; jj < 32; jj++) {
        bf16x4 v = *(const bf16x4*)(base + jj * 1024);
        const float al = alphaS[jj];
        acc.x += al * (float)v.x;
        acc.y += al * (float)v.y;
        acc.z += al * (float)v.z;
        acc.w += al * (float)v.w;
    }
    bf16x4 bb = { (__bf16)acc.x, (__bf16)acc.y, (__bf16)acc.z, (__bf16)acc.w };
    *(bf16x4*)(bagb + (size_t)b * 1024 + t * 4) = bb;

    float q = acc.x * acc.x + acc.y * acc.y + acc.z * acc.z + acc.w * acc.w;
    q = wsum(q);
    if ((t & 63) == 0) atomicAdd(&nbsq[b], q);
}

// ---- k4: MFMA 128x128 tile, BK=64 double-buffered, conflict-free LDS layout ----
// LDS slot layout (per 16KB A or B tile, 1024 x 16B slots):
//   slot s = Rb*128 + ks*64 + quad*16 + r  <->  global (row = base + Rb*16 + r,
//                                                col = k0 + ks*32 + quad*8, 8 elems)
// Fragment read for lane (m,quad): slot = Rb*128 + ks*64 + quad*16 + m
//   -> byte offset = lane*16 within each 1KB chunk: lane-contiguous, 0 bank conflicts.
// gll16 dest stays linear (wave-uniform base + lane*16); the permutation is applied
// on the per-lane GLOBAL source address (both-sides rule).
__global__ __launch_bounds__(256) void k4_gemm(
    const __bf16* __restrict__ repb, const __bf16* __restrict__ bagb,
    const float* __restrict__ nr, const float* __restrict__ nbsq,
    const float* __restrict__ temp, float* __restrict__ partial, float* __restrict__ diag,
    const __bf16* __restrict__ cwb, const float* __restrict__ bias, float* __restrict__ out)
{
    __shared__ __align__(16) char smem[65536];         // A0 16K | B0 16K | A1 16K | B1 16K
    const int bid = blockIdx.x;
    const int t = threadIdx.x, lane = t & 63, w = t >> 6;
    const int m = lane & 15, quad = lane >> 4;

    if (bid >= 512) {
        // ---- folded k3m: bag_out = bagb @ cwb^T + cls_b ---- (unchanged structure)
        __bf16* Al = (__bf16*)smem;
        __bf16* Bl = (__bf16*)(smem + 8192);
        const int r0 = (bid - 512) * 64;
        f32x4 acc[4] = {};
        const int i0 = t * 8;
        const int row0 = i0 >> 5, kk0 = i0 & 31;
        const __bf16* gA = bagb + (size_t)(r0 + row0) * 1024 + kk0;
        const __bf16* gB = cwb + (size_t)row0 * 1024 + kk0;
        for (int k0 = 0; k0 < 1024; k0 += 64) {
            __syncthreads();
            gll16(gA + k0,      Al + i0);
            gll16(gA + k0 + 32, Al + 2048 + i0);
            gll16(gB + k0,      Bl + i0);
            gll16(gB + k0 + 32, Bl + 2048 + i0);
            __syncthreads();
            #pragma unroll
            for (int ks = 0; ks < 2; ks++) {
                bf16x8 a = *(const bf16x8*)(&Al[ks * 2048 + (w * 16 + m) * 32 + quad * 8]);
                #pragma unroll
                for (int n = 0; n < 4; n++) {
                    bf16x8 bf = *(const bf16x8*)(&Bl[ks * 2048 + (n * 16 + m) * 32 + quad * 8]);
                    acc[n] = __builtin_amdgcn_mfma_f32_16x16x32_bf16(a, bf, acc[n], 0, 0, 0);
                }
            }
        }
        #pragma unroll
        for (int n = 0; n < 4; n++) {
            const int c = n * 16 + m;
            if (c < 53) {
                #pragma unroll
                for (int i = 0; i < 4; i++) {
                    const int r = r0 + w * 16 + quad * 4 + i;
                    out[(size_t)r * 53 + c] = acc[n][i] + bias[c];
                }
            }
        }
        return;
    }

    __bf16* A0 = (__bf16*)smem;
    __bf16* B0 = (__bf16*)(smem + 16384);
    __bf16* A1 = (__bf16*)(smem + 32768);
    __bf16* B1 = (__bf16*)(smem + 49152);

    const int xcd = bid & 7, slot = bid >> 3;
    const int cb = slot & 3, rb = (slot >> 2) * 8 + xcd;
    const int r0 = rb * 128, c0 = cb * 128;
    const int wr0 = (w & 1) * 64, wc0 = (w >> 1) * 64;

    // staging decode: thread t fills slots {t, t+256, t+512, t+768} of each tile
    int rowo[4], colo[4], ldso[4];
    #pragma unroll
    for (int u = 0; u < 4; u++) {
        const int s = u * 256 + t;
        rowo[u] = (s >> 7) * 16 + (s & 15);            // Rb*16 + r
        colo[u] = ((s >> 6) & 1) * 32 + ((s >> 4) & 3) * 8;  // ks*32 + quad*8
        ldso[u] = s * 8;                               // bf16 offset (16B slots)
    }
    const __bf16* gA = repb + (size_t)r0 * 1024;
    const __bf16* gB = bagb + (size_t)c0 * 1024;

    f32x4 acc[4][4] = {};

    auto STAGE = [&](__bf16* Ad, __bf16* Bd, int k0) {
        #pragma unroll
        for (int u = 0; u < 4; u++) {
            gll16(gA + (size_t)rowo[u] * 1024 + k0 + colo[u], Ad + ldso[u]);
            gll16(gB + (size_t)rowo[u] * 1024 + k0 + colo[u], Bd + ldso[u]);
        }
    };
    auto COMPUTE = [&](const __bf16* Ar, const __bf16* Br) {
        #pragma unroll
        for (int ks = 0; ks < 2; ks++) {
            bf16x8 a[4], bq[4];
            #pragma unroll
            for (int i = 0; i < 4; i++)
                a[i] = *(const bf16x8*)(Ar + (((wr0 >> 4) + i) * 128 + ks * 64 + quad * 16 + m) * 8);
            #pragma unroll
            for (int n = 0; n < 4; n++)
                bq[n] = *(const bf16x8*)(Br + (((wc0 >> 4) + n) * 128 + ks * 64 + quad * 16 + m) * 8);
            #pragma unroll
            for (int i = 0; i < 4; i++)
                #pragma unroll
                for (int n = 0; n < 4; n++)
                    acc[i][n] = __builtin_amdgcn_mfma_f32_16x16x32_bf16(a[i], bq[n], acc[i][n], 0, 0, 0);
        }
    };

    STAGE(A0, B0, 0);
    __syncthreads();                                   // drain vmcnt: buf0 ready
    for (int k0 = 0; k0 < 1024; k0 += 128) {
        STAGE(A1, B1, k0 + 64);                        // prefetch next (always valid: k0<=896)
        COMPUTE(A0, B0);
        __syncthreads();                               // buf1 ready; buf0 free
        if (k0 + 128 < 1024) STAGE(A0, B0, k0 + 128);
        COMPUTE(A1, B1);
        __syncthreads();
    }

    const float invT = 1.0f / *temp;
    float nrv[16];
    #pragma unroll
    for (int i = 0; i < 4; i++)
        #pragma unroll
        for (int g = 0; g < 4; g++)
            nrv[i * 4 + g] = nr[r0 + wr0 + i * 16 + quad * 4 + g];

    // each wave owns 64 rows = 2 bags; pair-sum (i,i+2) reduces them -> direct store
    const int rb2 = rb * 2 + (w & 1);                  // 0..255
    float* pbase = partial + (size_t)rb2 * 32 * 512;

    #pragma unroll
    for (int n = 0; n < 4; n++) {
        const int c_local = wc0 + n * 16 + m;
        const int cg = c0 + c_local;
        const float nbv = sqrtf(nbsq[cg]);
        #pragma unroll
        for (int i = 0; i < 2; i++) {                  // parity pairs (i, i+2)
            #pragma unroll
            for (int g = 0; g < 4; g++) {
                const int jj = i * 16 + quad * 4 + g;
                const int rg0 = r0 + wr0 + i * 16 + quad * 4 + g;
                const int rg2 = rg0 + 32;
                float e0 = __expf(acc[i][n][g]     / fmaxf(nbv * nrv[i * 4 + g],       1e-8f) * invT);
                float e2 = __expf(acc[i + 2][n][g] / fmaxf(nbv * nrv[(i + 2) * 4 + g], 1e-8f) * invT);
                pbase[(size_t)jj * 512 + cg] = e0 + e2;
                if ((rg0 >> 5) == cg) diag[(size_t)cg * 32 + jj] = e0;
                if ((rg2 >> 5) == cg) diag[(size_t)cg * 32 + jj] = e2;
            }
        }
    }
}

// ---- k5: reduce partial over rb2 (256) + loss terms; atomic accumulate into loss ----
__global__ __launch_bounds__(256) void k5_neg(
    const float* __restrict__ partial, const float* __restrict__ diag,
    const float* __restrict__ pos_sim, const float* __restrict__ temp,
    float* __restrict__ loss)
{
    const int ct = blockIdx.x & 7, j = blockIdx.x >> 3;
    const int t = threadIdx.x, lane = t & 63, w = t >> 6;
    const int bsub = t >> 4;                           // 0..15 (rb2-group of 16)
    const int cidx = t & 15;                           // x4 cols
    f32x4 acc = {};
    #pragma unroll 4
    for (int r = 0; r < 16; r++) {
        const int rb = bsub * 16 + r;
        f32x4 v = *(const f32x4*)(partial + ((size_t)rb * 32 + j) * 512 + ct * 64 + cidx * 4);
        acc += v;
    }
    #pragma unroll
    for (int k = 0; k < 4; k++) {
        acc[k] += __shfl_xor(acc[k], 16, 64);
        acc[k] += __shfl_xor(acc[k], 32, 64);
    }
    __shared__ float red[4][64];
    if (lane < 16) {
        #pragma unroll
        for (int k = 0; k < 4; k++) red[w][lane * 4 + k] = acc[k];
    }
    __syncthreads();

    if (t < 64) {
        const int c = ct * 64 + t;
        float S = red[0][t] + red[1][t] + red[2][t] + red[3][t];
        S -= diag[(size_t)c * 32 + j];                 // near-exact cancellation (f32)
        const float invT = 1.0f / *temp;
        const float lp = pos_sim[(c << 5) + j] * invT;
        float term = logf(__expf(lp) + S) - lp;
        term = wsum(term);
        if (t == 0) atomicAdd(loss, term * (1.0f / 16384.0f));
    }
}

extern "C" void kernel_launch(void* const* d_in, const int* in_sizes, int n_in,
                              void* d_out, int out_size, void* d_ws, size_t ws_size,
                              hipStream_t stream)
{
    const float* sent = (const float*)d_in[0];
    const float* aug  = (const float*)d_in[1];
    const float* rel  = (const float*)d_in[2];
    const float* clsw = (const float*)d_in[3];
    const float* clsb = (const float*)d_in[4];
    const int*   lab  = (const int*)d_in[5];
    const float* temp = (const float*)d_in[6];
    float* out = (float*)d_out;

    char* ws = (char*)d_ws;
    __bf16* bagb    = (__bf16*)(ws);                           // 1 MB
    float*  nbsq    = (float*)(ws + (1u << 20));               // 2 KB
    float*  nr      = (float*)(ws + (1u << 20) + 64 * 1024);   // 64 KB
    float*  pos     = (float*)(ws + (1u << 20) + 128 * 1024);  // 64 KB
    __bf16* cwb     = (__bf16*)(ws + (1u << 20) + 192 * 1024); // 128 KB
    float*  scoreg  = (float*)(ws + (1u << 20) + 320 * 1024);  // 64 KB
    float*  diag    = (float*)(ws + (2u << 20) + 64 * 1024);   // 64 KB
    __bf16* repb    = (__bf16*)(ws + (4u << 20));              // 32 MB
    float*  partial = (float*)(ws + (36u << 20));              // 16 MB (256 rb2)

    float* loss = out + 27136;

    ka     <<<4096, 256, 0, stream>>>(sent, aug, rel, lab, repb, nr, pos, scoreg,
                                      clsw, cwb, nbsq, loss);
    kb     <<<512, 256, 0, stream>>>(repb, scoreg, bagb, nbsq);
    k4_gemm<<<520, 256, 0, stream>>>(repb, bagb, nr, nbsq, temp, partial, diag,
                                     cwb, clsb, out);
    k5_neg <<<256, 256, 0, stream>>>(partial, diag, pos, temp, loss);
}

// Round 2
// 199.418 us; speedup vs baseline: 1.0671x; 1.0671x over previous
//
#include <hip/hip_runtime.h>
#include <hip/hip_bf16.h>

// Shapes: B=512, BAG=32, H=1024, C=53.  EPS=1e-8, scale=sqrt(1024)=32.
// Out: bag_out (512*53=27136) f32, then cl_loss scalar -> 27137 floats.

typedef __bf16 bf16x8 __attribute__((ext_vector_type(8)));
typedef __bf16 bf16x4 __attribute__((ext_vector_type(4)));
typedef float  f32x4  __attribute__((ext_vector_type(4)));

__device__ inline float wsum(float v) {
    #pragma unroll
    for (int off = 32; off > 0; off >>= 1) v += __shfl_xor(v, off, 64);
    return v;
}

__device__ inline void gll16(const void* g, void* l) {
    __builtin_amdgcn_global_load_lds((const __attribute__((address_space(1))) void*)g,
                                     (__attribute__((address_space(3))) void*)l, 16, 0, 0);
}

__device__ inline f32x4 ntld(const float* p) {
    return __builtin_nontemporal_load((const f32x4*)p);
}

// ---- ka: streaming pass (1 row/wave, NT input loads) + folded k0 ----
__global__ __launch_bounds__(256) void ka(
    const float* __restrict__ sent, const float* __restrict__ aug,
    const float* __restrict__ rel_table, const int* __restrict__ labels,
    __bf16* __restrict__ repb, float* __restrict__ nr, float* __restrict__ pos_sim,
    float* __restrict__ scoreg,
    const float* __restrict__ clsw, __bf16* __restrict__ cwb,
    float* __restrict__ nbsq, float* __restrict__ loss)
{
    const int t = threadIdx.x;
    // folded k0: blocks 0..255 convert cls_w (padded to 64 rows); block 256 zeroes scalars
    if (blockIdx.x < 256) {
        const int i = blockIdx.x * 256 + t;
        cwb[i] = (i < 53 * 1024) ? (__bf16)clsw[i] : (__bf16)0.0f;
    } else if (blockIdx.x == 256) {
        nbsq[t] = 0.0f; nbsq[256 + t] = 0.0f;
        if (t == 0) *loss = 0.0f;
    }

    const int w = t >> 6, lane = t & 63;
    const int row = blockIdx.x * 4 + w;                // 0..16383 (wave-uniform)
    const int b = row >> 5;
    const size_t rbase = (size_t)row * 1024;
    const float* srow = sent + rbase;
    const float* arow = aug + rbase;
    const float* relp = rel_table + (size_t)labels[b] * 1024;

    float P = 0.f, R = 0.f, A = 0.f, D = 0.f;
    #pragma unroll
    for (int i = 0; i < 4; i++) {
        const int h = i * 256 + lane * 4;
        f32x4 v  = ntld(srow + h);                     // nt: read-once, don't pollute L3
        f32x4 a  = ntld(arow + h);
        f32x4 rl = *(const f32x4*)(relp + h);          // reused across bags: keep cached
        P += v.x * rl.x + v.y * rl.y + v.z * rl.z + v.w * rl.w;
        R += v.x * v.x + v.y * v.y + v.z * v.z + v.w * v.w;
        A += a.x * a.x + a.y * a.y + a.z * a.z + a.w * a.w;
        D += v.x * a.x + v.y * a.y + v.z * a.z + v.w * a.w;
        bf16x4 vb = { (__bf16)v.x, (__bf16)v.y, (__bf16)v.z, (__bf16)v.w };
        *(bf16x4*)(repb + rbase + h) = vb;
    }
    #pragma unroll
    for (int off = 32; off > 0; off >>= 1) {
        P += __shfl_xor(P, off, 64);
        R += __shfl_xor(R, off, 64);
        A += __shfl_xor(A, off, 64);
        D += __shfl_xor(D, off, 64);
    }
    if (lane == 0) {
        scoreg[row] = P * (1.0f / 32.0f);              // /sqrt(H)
        float nrv = sqrtf(R), nav = sqrtf(A);
        nr[row] = nrv;
        pos_sim[row] = D / fmaxf(nrv * nav, 1e-8f);
    }
}

// ---- kb: per-b softmax + bag from bf16 repb (L2/L3-hot) ----
__global__ __launch_bounds__(256) void kb(
    const __bf16* __restrict__ repb, const float* __restrict__ scoreg,
    __bf16* __restrict__ bagb, float* __restrict__ nbsq)
{
    __shared__ float alphaS[32];
    const int b = blockIdx.x, t = threadIdx.x;
    if (t < 32) {
        float sj = scoreg[b * 32 + t];
        float m = sj;
        #pragma unroll
        for (int off = 16; off > 0; off >>= 1) m = fmaxf(m, __shfl_xor(m, off, 32));
        float e = __expf(sj - m);
        float sum = e;
        #pragma unroll
        for (int off = 16; off > 0; off >>= 1) sum += __shfl_xor(sum, off, 32);
        alphaS[t] = e / sum;
    }
    __syncthreads();

    f32x4 acc = {};
    const __bf16* base = repb + (size_t)b * 32 * 1024 + t * 4;
    #pragma unroll 8
    for (int jj = 0; jj < 32; jj++) {
        bf16x4 v = *(const bf16x4*)(base + jj * 1024);
        const float al = alphaS[jj];
        acc.x += al * (float)v.x;
        acc.y += al * (float)v.y;
        acc.z += al * (float)v.z;
        acc.w += al * (float)v.w;
    }
    bf16x4 bb = { (__bf16)acc.x, (__bf16)acc.y, (__bf16)acc.z, (__bf16)acc.w };
    *(bf16x4*)(bagb + (size_t)b * 1024 + t * 4) = bb;

    float q = acc.x * acc.x + acc.y * acc.y + acc.z * acc.z + acc.w * acc.w;
    q = wsum(q);
    if ((t & 63) == 0) atomicAdd(&nbsq[b], q);
}

// ---- k4: MFMA 128x128 tile, BK=32, triple-buffered counted-vmcnt pipeline ----
// LDS: buf0 0..16K | buf1 16..32K | buf2 32..48K ; negp overlays 32..64K
// (buf2's last read is step 29; two raw barriers separate it from negp writes).
// Each 16KB buf: A-tile [0..8K) = 512 slots of 16B, slot s=(row*4+kg'); B-tile [8K..16K).
// Swizzle: slot (row,kg') holds global cols 8*(kg' ^ rho(row)), rho=(row>>1)&3.
// Staging src: thread t -> row t>>2, col 8*((t&3)^((t>>3)&3)): lanes 4q..4q+3 still
// cover one 64B segment (coalescing preserved); gll16 dest linear (both-sides rule).
// Fragment read slot = row*4 + (quad^rho(m)) -> bank groups 2-way only (free).
__global__ __launch_bounds__(256) void k4_gemm(
    const __bf16* __restrict__ repb, const __bf16* __restrict__ bagb,
    const float* __restrict__ nr, const float* __restrict__ nbsq,
    const float* __restrict__ temp, float* __restrict__ partial, float* __restrict__ diag,
    const __bf16* __restrict__ cwb, const float* __restrict__ bias, float* __restrict__ out)
{
    __shared__ __align__(16) char smem[65536];
    const int bid = blockIdx.x;
    const int t = threadIdx.x, lane = t & 63, w = t >> 6;
    const int m = lane & 15, quad = lane >> 4;

    if (bid >= 512) {
        // ---- folded k3m: bag_out = bagb @ cwb^T + cls_b ----
        __bf16* Al = (__bf16*)smem;
        __bf16* Bl = (__bf16*)(smem + 8192);
        const int r0 = (bid - 512) * 64;
        f32x4 acc[4] = {};
        const int i0 = t * 8;
        const int row0 = i0 >> 5, kk0 = i0 & 31;
        const __bf16* gA = bagb + (size_t)(r0 + row0) * 1024 + kk0;
        const __bf16* gB = cwb + (size_t)row0 * 1024 + kk0;
        for (int k0 = 0; k0 < 1024; k0 += 64) {
            __syncthreads();
            gll16(gA + k0,      Al + i0);
            gll16(gA + k0 + 32, Al + 2048 + i0);
            gll16(gB + k0,      Bl + i0);
            gll16(gB + k0 + 32, Bl + 2048 + i0);
            __syncthreads();
            #pragma unroll
            for (int ks = 0; ks < 2; ks++) {
                bf16x8 a = *(const bf16x8*)(&Al[ks * 2048 + (w * 16 + m) * 32 + quad * 8]);
                #pragma unroll
                for (int n = 0; n < 4; n++) {
                    bf16x8 bf = *(const bf16x8*)(&Bl[ks * 2048 + (n * 16 + m) * 32 + quad * 8]);
                    acc[n] = __builtin_amdgcn_mfma_f32_16x16x32_bf16(a, bf, acc[n], 0, 0, 0);
                }
            }
        }
        #pragma unroll
        for (int n = 0; n < 4; n++) {
            const int c = n * 16 + m;
            if (c < 53) {
                #pragma unroll
                for (int i = 0; i < 4; i++) {
                    const int r = r0 + w * 16 + quad * 4 + i;
                    out[(size_t)r * 53 + c] = acc[n][i] + bias[c];
                }
            }
        }
        return;
    }

    __bf16* Bu0 = (__bf16*)smem;
    __bf16* Bu1 = (__bf16*)(smem + 16384);
    __bf16* Bu2 = (__bf16*)(smem + 32768);
    float (*negp)[32][128] = (float (*)[32][128])(smem + 32768);

    const int xcd = bid & 7, slot = bid >> 3;
    const int cb = slot & 3, rb = (slot >> 2) * 8 + xcd;
    const int r0 = rb * 128, c0 = cb * 128;
    const int wr0 = (w & 1) * 64, wc0 = (w >> 1) * 64;
    const int half = w & 1;

    // staging: lane-adjacent rows, XOR-swizzled 16B k-group within each row
    const int swc = 8 * ((t & 3) ^ ((t >> 3) & 3));
    const size_t sOff = (size_t)(t >> 2) * 1024 + swc;
    const __bf16* pA0 = repb + (size_t)r0 * 1024 + sOff;
    const __bf16* pA1 = pA0 + 64 * 1024;
    const __bf16* pB0 = bagb + (size_t)c0 * 1024 + sOff;
    const __bf16* pB1 = pB0 + 64 * 1024;
    const int d0 = t * 8, d1 = 2048 + t * 8, d2 = 4096 + t * 8, d3 = 6144 + t * 8;

    // fragment-read offsets (bf16 units)
    const int rho = (m >> 1) & 3;
    const int offA = ((wr0 + m) * 4 + (quad ^ rho)) * 8;
    const int offB = 4096 + ((wc0 + m) * 4 + (quad ^ rho)) * 8;

    f32x4 acc[4][4] = {};

    #define STG(buf, s) do { const int kk_ = (s) * 32;                      \
        gll16(pA0 + kk_, (buf) + d0); gll16(pA1 + kk_, (buf) + d1);         \
        gll16(pB0 + kk_, (buf) + d2); gll16(pB1 + kk_, (buf) + d3); } while (0)

    #define CMP(buf) do { bf16x8 av_[4], bv_[4];                            \
        _Pragma("unroll") for (int i_ = 0; i_ < 4; i_++)                    \
            av_[i_] = *(const bf16x8*)((buf) + offA + i_ * 512);            \
        _Pragma("unroll") for (int n_ = 0; n_ < 4; n_++)                    \
            bv_[n_] = *(const bf16x8*)((buf) + offB + n_ * 512);            \
        _Pragma("unroll") for (int i_ = 0; i_ < 4; i_++)                    \
        _Pragma("unroll") for (int n_ = 0; n_ < 4; n_++)                    \
            acc[i_][n_] = __builtin_amdgcn_mfma_f32_16x16x32_bf16(          \
                av_[i_], bv_[n_], acc[i_][n_], 0, 0, 0); } while (0)

    #define FENCE(N) do { __builtin_amdgcn_sched_barrier(0);                \
        asm volatile("s_waitcnt vmcnt(" #N ")" ::: "memory");               \
        __builtin_amdgcn_s_barrier();                                       \
        __builtin_amdgcn_sched_barrier(0); } while (0)

    STG(Bu0, 0);
    STG(Bu1, 1);
    FENCE(4);                                   // step 0 resident; step 1 in flight
    #pragma unroll 1
    for (int s = 0; s < 28; s += 3) {           // s = 0,3,...,27: computes steps s..s+2
        STG(Bu2, s + 2); CMP(Bu0); FENCE(4);    // retire s+1, keep s+2 flying
        STG(Bu0, s + 3); CMP(Bu1); FENCE(4);
        STG(Bu1, s + 4); CMP(Bu2); FENCE(4);    // s=27 stages step 31 (max)
    }
    CMP(Bu0);                                   // step 30 (resident via last FENCE(4))
    FENCE(0);                                   // retire step 31
    CMP(Bu1);                                   // step 31

    const float invT = 1.0f / *temp;
    float nrv[16];
    #pragma unroll
    for (int i = 0; i < 4; i++)
        #pragma unroll
        for (int g = 0; g < 4; g++)
            nrv[i * 4 + g] = nr[r0 + wr0 + i * 16 + quad * 4 + g];

    #pragma unroll
    for (int n = 0; n < 4; n++) {
        const int c_local = wc0 + n * 16 + m;
        const int cg = c0 + c_local;
        const float nbv = sqrtf(nbsq[cg]);
        #pragma unroll
        for (int i = 0; i < 2; i++) {                  // parity pairs (i, i+2)
            #pragma unroll
            for (int g = 0; g < 4; g++) {
                const int jj = i * 16 + quad * 4 + g;
                const int rg0 = r0 + wr0 + i * 16 + quad * 4 + g;
                const int rg2 = rg0 + 32;
                float e0 = __expf(acc[i][n][g]     / fmaxf(nbv * nrv[i * 4 + g],       1e-8f) * invT);
                float e2 = __expf(acc[i + 2][n][g] / fmaxf(nbv * nrv[(i + 2) * 4 + g], 1e-8f) * invT);
                negp[half][jj][c_local] = e0 + e2;
                if ((rg0 >> 5) == cg) diag[(size_t)cg * 32 + jj] = e0;
                if ((rg2 >> 5) == cg) diag[(size_t)cg * 32 + jj] = e2;
            }
        }
    }
    __syncthreads();

    float* pout = partial + (size_t)rb * 32 * 512 + c0;
    #pragma unroll
    for (int v = 0; v < 4; v++) {
        const int idx = v * 1024 + t * 4;              // 0..4095
        const int jj = idx >> 7, cl = idx & 127;
        f32x4 a = *(const f32x4*)(&negp[0][jj][cl]);
        f32x4 bq = *(const f32x4*)(&negp[1][jj][cl]);
        f32x4 s = a + bq;
        *(f32x4*)(pout + (size_t)jj * 512 + cl) = s;
    }
    #undef STG
    #undef CMP
    #undef FENCE
}

// ---- k5: reduce partial over rb (128) + loss terms; atomic accumulate into loss ----
__global__ __launch_bounds__(256) void k5_neg(
    const float* __restrict__ partial, const float* __restrict__ diag,
    const float* __restrict__ pos_sim, const float* __restrict__ temp,
    float* __restrict__ loss)
{
    const int ct = blockIdx.x & 7, j = blockIdx.x >> 3;
    const int t = threadIdx.x, lane = t & 63, w = t >> 6;
    const int bsub = t >> 4;                           // 0..15 (rb-group of 8)
    const int cidx = t & 15;                           // x4 cols
    f32x4 acc = {};
    #pragma unroll 4
    for (int r = 0; r < 8; r++) {
        const int rb = bsub * 8 + r;
        f32x4 v = *(const f32x4*)(partial + ((size_t)rb * 32 + j) * 512 + ct * 64 + cidx * 4);
        acc += v;
    }
    #pragma unroll
    for (int k = 0; k < 4; k++) {
        acc[k] += __shfl_xor(acc[k], 16, 64);
        acc[k] += __shfl_xor(acc[k], 32, 64);
    }
    __shared__ float red[4][64];
    if (lane < 16) {
        #pragma unroll
        for (int k = 0; k < 4; k++) red[w][lane * 4 + k] = acc[k];
    }
    __syncthreads();

    if (t < 64) {
        const int c = ct * 64 + t;
        float S = red[0][t] + red[1][t] + red[2][t] + red[3][t];
        S -= diag[(size_t)c * 32 + j];                 // near-exact cancellation (f32)
        const float invT = 1.0f / *temp;
        const float lp = pos_sim[(c << 5) + j] * invT;
        float term = logf(__expf(lp) + S) - lp;
        term = wsum(term);
        if (t == 0) atomicAdd(loss, term * (1.0f / 16384.0f));
    }
}

extern "C" void kernel_launch(void* const* d_in, const int* in_sizes, int n_in,
                              void* d_out, int out_size, void* d_ws, size_t ws_size,
                              hipStream_t stream)
{
    const float* sent = (const float*)d_in[0];
    const float* aug  = (const float*)d_in[1];
    const float* rel  = (const float*)d_in[2];
    const float* clsw = (const float*)d_in[3];
    const float* clsb = (const float*)d_in[4];
    const int*   lab  = (const int*)d_in[5];
    const float* temp = (const float*)d_in[6];
    float* out = (float*)d_out;

    char* ws = (char*)d_ws;
    __bf16* bagb    = (__bf16*)(ws);                           // 1 MB
    float*  nbsq    = (float*)(ws + (1u << 20));               // 2 KB
    float*  nr      = (float*)(ws + (1u << 20) + 64 * 1024);   // 64 KB
    float*  pos     = (float*)(ws + (1u << 20) + 128 * 1024);  // 64 KB
    __bf16* cwb     = (__bf16*)(ws + (1u << 20) + 192 * 1024); // 128 KB
    float*  scoreg  = (float*)(ws + (1u << 20) + 320 * 1024);  // 64 KB
    float*  diag    = (float*)(ws + (2u << 20) + 64 * 1024);   // 64 KB
    __bf16* repb    = (__bf16*)(ws + (4u << 20));              // 32 MB
    float*  partial = (float*)(ws + (36u << 20));              // 8 MB

    float* loss = out + 27136;

    ka     <<<4096, 256, 0, stream>>>(sent, aug, rel, lab, repb, nr, pos, scoreg,
                                      clsw, cwb, nbsq, loss);
    kb     <<<512, 256, 0, stream>>>(repb, scoreg, bagb, nbsq);
    k4_gemm<<<520, 256, 0, stream>>>(repb, bagb, nr, nbsq, temp, partial, diag,
                                     cwb, clsb, out);
    k5_neg <<<256, 256, 0, stream>>>(partial, diag, pos, temp, loss);
}

// Round 3
// 194.740 us; speedup vs baseline: 1.0927x; 1.0240x over previous
//
#include <hip/hip_runtime.h>
#include <hip/hip_bf16.h>

// Shapes: B=512, BAG=32, H=1024, C=53.  EPS=1e-8, scale=sqrt(1024)=32.
// Out: bag_out (512*53=27136) f32, then cl_loss scalar -> 27137 floats.

typedef __bf16 bf16x8 __attribute__((ext_vector_type(8)));
typedef __bf16 bf16x4 __attribute__((ext_vector_type(4)));
typedef __bf16 bf16x2 __attribute__((ext_vector_type(2)));
typedef float  f32x4  __attribute__((ext_vector_type(4)));

__device__ inline float wsum(float v) {
    #pragma unroll
    for (int off = 32; off > 0; off >>= 1) v += __shfl_xor(v, off, 64);
    return v;
}

__device__ inline void gll16(const void* g, void* l) {
    __builtin_amdgcn_global_load_lds((const __attribute__((address_space(1))) void*)g,
                                     (__attribute__((address_space(3))) void*)l, 16, 0, 0);
}

__device__ inline f32x4 ntld(const float* p) {
    return __builtin_nontemporal_load((const f32x4*)p);
}

// ---- kab: merged streaming pass + per-bag softmax/bag (one bag per block) ----
// 8 waves x 4 rows = 32 rows/bag. rep rows held in 64KB LDS (bf16) so the bag
// accumulation needs no global re-read (was kb's 32MB repb pass).
__global__ __launch_bounds__(512, 4) void kab(
    const float* __restrict__ sent, const float* __restrict__ aug,
    const float* __restrict__ rel_table, const int* __restrict__ labels,
    __bf16* __restrict__ repb, float* __restrict__ nr, float* __restrict__ pos_sim,
    const float* __restrict__ clsw, __bf16* __restrict__ cwb,
    __bf16* __restrict__ bagb, float* __restrict__ nbsq, float* __restrict__ loss)
{
    __shared__ __align__(16) __bf16 repS[32][1024];    // 64 KB
    __shared__ float scoreS[32], alphaS[32], redS[8];
    const int b = blockIdx.x, t = threadIdx.x;
    const int w = t >> 6, lane = t & 63;

    // folded k0: blocks 0..127 convert cls_w (padded to 64 rows); block 0 zeroes loss
    if (b < 128) {
        const int i = b * 512 + t;
        cwb[i] = (i < 53 * 1024) ? (__bf16)clsw[i] : (__bf16)0.0f;
        if (b == 0 && t == 0) *loss = 0.0f;
    }

    const float* relp = rel_table + (size_t)labels[b] * 1024;
    #pragma unroll
    for (int rr = 0; rr < 4; rr++) {
        const int j = w * 4 + rr;                      // row within bag
        const size_t rbase = ((size_t)b * 32 + j) * 1024;
        const float* srow = sent + rbase;
        const float* arow = aug + rbase;
        float P = 0.f, R = 0.f, A = 0.f, D = 0.f;
        #pragma unroll
        for (int i = 0; i < 4; i++) {
            const int h = i * 256 + lane * 4;
            f32x4 v  = ntld(srow + h);                 // nt: read-once
            f32x4 a  = ntld(arow + h);
            f32x4 rl = *(const f32x4*)(relp + h);      // L1-hot across rows
            P += v.x * rl.x + v.y * rl.y + v.z * rl.z + v.w * rl.w;
            R += v.x * v.x + v.y * v.y + v.z * v.z + v.w * v.w;
            A += a.x * a.x + a.y * a.y + a.z * a.z + a.w * a.w;
            D += v.x * a.x + v.y * a.y + v.z * a.z + v.w * a.w;
            bf16x4 vb = { (__bf16)v.x, (__bf16)v.y, (__bf16)v.z, (__bf16)v.w };
            *(bf16x4*)(&repS[j][h]) = vb;
            *(bf16x4*)(repb + rbase + h) = vb;
        }
        #pragma unroll
        for (int off = 32; off > 0; off >>= 1) {
            P += __shfl_xor(P, off, 64);
            R += __shfl_xor(R, off, 64);
            A += __shfl_xor(A, off, 64);
            D += __shfl_xor(D, off, 64);
        }
        if (lane == 0) {
            scoreS[j] = P * (1.0f / 32.0f);            // /sqrt(H)
            float nrv = sqrtf(R), nav = sqrtf(A);
            nr[b * 32 + j] = nrv;
            pos_sim[b * 32 + j] = D / fmaxf(nrv * nav, 1e-8f);
        }
    }
    __syncthreads();

    if (t < 32) {
        float sj = scoreS[t], mx = sj;
        #pragma unroll
        for (int off = 16; off > 0; off >>= 1) mx = fmaxf(mx, __shfl_xor(mx, off, 32));
        float e = __expf(sj - mx), sm = e;
        #pragma unroll
        for (int off = 16; off > 0; off >>= 1) sm += __shfl_xor(sm, off, 32);
        alphaS[t] = e / sm;
    }
    __syncthreads();

    // bag: thread t owns H positions {2t, 2t+1}; LDS reads 2-way bank = free
    float b0 = 0.f, b1 = 0.f;
    #pragma unroll 8
    for (int j = 0; j < 32; j++) {
        const float al = alphaS[j];
        bf16x2 v = *(const bf16x2*)(&repS[j][t * 2]);
        b0 += al * (float)v.x;
        b1 += al * (float)v.y;
    }
    bf16x2 bb = { (__bf16)b0, (__bf16)b1 };
    *(bf16x2*)(bagb + (size_t)b * 1024 + t * 2) = bb;

    float q = b0 * b0 + b1 * b1;
    q = wsum(q);
    if (lane == 0) redS[w] = q;
    __syncthreads();
    if (t == 0)
        nbsq[b] = redS[0] + redS[1] + redS[2] + redS[3]
                + redS[4] + redS[5] + redS[6] + redS[7];
}

// ---- k4: MFMA 128x128 tile, BK=32, triple-buffered counted-vmcnt pipeline ----
// 512 threads / 8 waves (wave = 64x32 sub-tile) -> 16 waves/CU at 2 blocks/CU:
// doubles latency hiding vs the 4-wave version. Staging: threads 0..255 stage A,
// 256..511 stage B, 2 gll16/thread/step -> FENCE(2) keeps newest step in flight.
// Swizzle unchanged: slot (row,kg') holds cols 8*(kg'^rho(row)), rho=(row>>1)&3;
// rho(row)==rho(row+64) so both slots of a thread share one source column.
__global__ __launch_bounds__(512, 4) void k4_gemm(
    const __bf16* __restrict__ repb, const __bf16* __restrict__ bagb,
    const float* __restrict__ nr, const float* __restrict__ nbsq,
    const float* __restrict__ temp, float* __restrict__ partial, float* __restrict__ diag,
    const __bf16* __restrict__ cwb, const float* __restrict__ bias, float* __restrict__ out)
{
    __shared__ __align__(16) char smem[65536];
    const int bid = blockIdx.x;
    const int t = threadIdx.x, lane = t & 63, w = t >> 6;
    const int m = lane & 15, quad = lane >> 4;

    if (bid >= 512) {
        // ---- folded k3m: bag_out = bagb @ cwb^T + cls_b (t<256 active, rest ride barriers) ----
        __bf16* Al = (__bf16*)smem;
        __bf16* Bl = (__bf16*)(smem + 8192);
        const int r0 = (bid - 512) * 64;
        f32x4 acc[4] = {};
        const int i0 = (t & 255) * 8;
        const int row0 = i0 >> 5, kk0 = i0 & 31;
        const __bf16* gA = bagb + (size_t)(r0 + row0) * 1024 + kk0;
        const __bf16* gB = cwb + (size_t)row0 * 1024 + kk0;
        const bool act = (t < 256);
        for (int k0 = 0; k0 < 1024; k0 += 64) {
            __syncthreads();
            if (act) {
                gll16(gA + k0,      Al + i0);
                gll16(gA + k0 + 32, Al + 2048 + i0);
                gll16(gB + k0,      Bl + i0);
                gll16(gB + k0 + 32, Bl + 2048 + i0);
            }
            __syncthreads();
            if (act) {
                #pragma unroll
                for (int ks = 0; ks < 2; ks++) {
                    bf16x8 a = *(const bf16x8*)(&Al[ks * 2048 + (w * 16 + m) * 32 + quad * 8]);
                    #pragma unroll
                    for (int n = 0; n < 4; n++) {
                        bf16x8 bf = *(const bf16x8*)(&Bl[ks * 2048 + (n * 16 + m) * 32 + quad * 8]);
                        acc[n] = __builtin_amdgcn_mfma_f32_16x16x32_bf16(a, bf, acc[n], 0, 0, 0);
                    }
                }
            }
        }
        if (act) {
            #pragma unroll
            for (int n = 0; n < 4; n++) {
                const int c = n * 16 + m;
                if (c < 53) {
                    #pragma unroll
                    for (int i = 0; i < 4; i++) {
                        const int r = r0 + w * 16 + quad * 4 + i;
                        out[(size_t)r * 53 + c] = acc[n][i] + bias[c];
                    }
                }
            }
        }
        return;
    }

    __bf16* Bu0 = (__bf16*)smem;
    __bf16* Bu1 = (__bf16*)(smem + 16384);
    __bf16* Bu2 = (__bf16*)(smem + 32768);
    float (*negp)[32][128] = (float (*)[32][128])(smem + 32768);  // overlays Bu2

    const int xcd = bid & 7, slot = bid >> 3;
    const int cb = slot & 3, rb = (slot >> 2) * 8 + xcd;
    const int r0 = rb * 128, c0 = cb * 128;
    const int wr0 = (w & 1) * 64, wc0 = (w >> 1) * 32;
    const int half = w & 1;

    // staging: threads 0..255 -> A slots {tt, tt+256}; 256..511 -> B ditto
    const int tt = t & 255;
    const bool isB = (t >= 256);
    const int srow = tt >> 2;                          // 0..63
    const int scol = 8 * ((tt & 3) ^ ((srow >> 1) & 3));
    const __bf16* g0 = (isB ? bagb + (size_t)(c0 + srow) * 1024
                            : repb + (size_t)(r0 + srow) * 1024) + scol;
    const __bf16* g1 = g0 + 64 * 1024;                 // row + 64 (same swizzle)
    const int d0 = (isB ? 4096 : 0) + tt * 8;
    const int d1 = d0 + 2048;

    // fragment-read offsets (bf16 units)
    const int rho = (m >> 1) & 3;
    const int offA = ((wr0 + m) * 4 + (quad ^ rho)) * 8;
    const int offB = 4096 + ((wc0 + m) * 4 + (quad ^ rho)) * 8;

    f32x4 acc[4][2] = {};

    #define STG(buf, s) do { const int kk_ = (s) * 32;                      \
        gll16(g0 + kk_, (buf) + d0); gll16(g1 + kk_, (buf) + d1); } while (0)

    #define CMP(buf) do { bf16x8 av_[4], bv_[2];                            \
        _Pragma("unroll") for (int i_ = 0; i_ < 4; i_++)                    \
            av_[i_] = *(const bf16x8*)((buf) + offA + i_ * 512);            \
        _Pragma("unroll") for (int n_ = 0; n_ < 2; n_++)                    \
            bv_[n_] = *(const bf16x8*)((buf) + offB + n_ * 512);            \
        _Pragma("unroll") for (int i_ = 0; i_ < 4; i_++)                    \
        _Pragma("unroll") for (int n_ = 0; n_ < 2; n_++)                    \
            acc[i_][n_] = __builtin_amdgcn_mfma_f32_16x16x32_bf16(          \
                av_[i_], bv_[n_], acc[i_][n_], 0, 0, 0); } while (0)

    #define FENCE(N) do { __builtin_amdgcn_sched_barrier(0);                \
        asm volatile("s_waitcnt vmcnt(" #N ")" ::: "memory");               \
        __builtin_amdgcn_s_barrier();                                       \
        __builtin_amdgcn_sched_barrier(0); } while (0)

    STG(Bu0, 0);
    STG(Bu1, 1);
    FENCE(2);                                   // step 0 resident; step 1 in flight
    #pragma unroll 1
    for (int s = 0; s < 28; s += 3) {           // computes steps s..s+2
        STG(Bu2, s + 2); CMP(Bu0); FENCE(2);
        STG(Bu0, s + 3); CMP(Bu1); FENCE(2);
        STG(Bu1, s + 4); CMP(Bu2); FENCE(2);
    }
    CMP(Bu0);                                   // step 30
    FENCE(0);                                   // retire step 31
    CMP(Bu1);                                   // step 31

    const float invT = 1.0f / *temp;
    float nrv[16];
    #pragma unroll
    for (int i = 0; i < 4; i++)
        #pragma unroll
        for (int g = 0; g < 4; g++)
            nrv[i * 4 + g] = nr[r0 + wr0 + i * 16 + quad * 4 + g];

    #pragma unroll
    for (int n = 0; n < 2; n++) {
        const int c_local = wc0 + n * 16 + m;
        const int cg = c0 + c_local;
        const float nbv = sqrtf(nbsq[cg]);
        #pragma unroll
        for (int i = 0; i < 2; i++) {                  // parity pairs (i, i+2)
            #pragma unroll
            for (int g = 0; g < 4; g++) {
                const int jj = i * 16 + quad * 4 + g;
                const int rg0 = r0 + wr0 + i * 16 + quad * 4 + g;
                const int rg2 = rg0 + 32;
                float e0 = __expf(acc[i][n][g]     / fmaxf(nbv * nrv[i * 4 + g],       1e-8f) * invT);
                float e2 = __expf(acc[i + 2][n][g] / fmaxf(nbv * nrv[(i + 2) * 4 + g], 1e-8f) * invT);
                negp[half][jj][c_local] = e0 + e2;
                if ((rg0 >> 5) == cg) diag[(size_t)cg * 32 + jj] = e0;
                if ((rg2 >> 5) == cg) diag[(size_t)cg * 32 + jj] = e2;
            }
        }
    }
    __syncthreads();

    float* pout = partial + (size_t)rb * 32 * 512 + c0;
    #pragma unroll
    for (int v = 0; v < 2; v++) {
        const int idx = v * 2048 + t * 4;              // 0..4095
        const int jj = idx >> 7, cl = idx & 127;
        f32x4 a = *(const f32x4*)(&negp[0][jj][cl]);
        f32x4 bq = *(const f32x4*)(&negp[1][jj][cl]);
        f32x4 s = a + bq;
        *(f32x4*)(pout + (size_t)jj * 512 + cl) = s;
    }
    #undef STG
    #undef CMP
    #undef FENCE
}

// ---- k5: reduce partial over rb (128) + loss terms; atomic accumulate into loss ----
__global__ __launch_bounds__(256) void k5_neg(
    const float* __restrict__ partial, const float* __restrict__ diag,
    const float* __restrict__ pos_sim, const float* __restrict__ temp,
    float* __restrict__ loss)
{
    const int ct = blockIdx.x & 7, j = blockIdx.x >> 3;
    const int t = threadIdx.x, lane = t & 63, w = t >> 6;
    const int bsub = t >> 4;                           // 0..15 (rb-group of 8)
    const int cidx = t & 15;                           // x4 cols
    f32x4 acc = {};
    #pragma unroll 4
    for (int r = 0; r < 8; r++) {
        const int rb = bsub * 8 + r;
        f32x4 v = *(const f32x4*)(partial + ((size_t)rb * 32 + j) * 512 + ct * 64 + cidx * 4);
        acc += v;
    }
    #pragma unroll
    for (int k = 0; k < 4; k++) {
        acc[k] += __shfl_xor(acc[k], 16, 64);
        acc[k] += __shfl_xor(acc[k], 32, 64);
    }
    __shared__ float red[4][64];
    if (lane < 16) {
        #pragma unroll
        for (int k = 0; k < 4; k++) red[w][lane * 4 + k] = acc[k];
    }
    __syncthreads();

    if (t < 64) {
        const int c = ct * 64 + t;
        float S = red[0][t] + red[1][t] + red[2][t] + red[3][t];
        S -= diag[(size_t)c * 32 + j];                 // near-exact cancellation (f32)
        const float invT = 1.0f / *temp;
        const float lp = pos_sim[(c << 5) + j] * invT;
        float term = logf(__expf(lp) + S) - lp;
        term = wsum(term);
        if (t == 0) atomicAdd(loss, term * (1.0f / 16384.0f));
    }
}

extern "C" void kernel_launch(void* const* d_in, const int* in_sizes, int n_in,
                              void* d_out, int out_size, void* d_ws, size_t ws_size,
                              hipStream_t stream)
{
    const float* sent = (const float*)d_in[0];
    const float* aug  = (const float*)d_in[1];
    const float* rel  = (const float*)d_in[2];
    const float* clsw = (const float*)d_in[3];
    const float* clsb = (const float*)d_in[4];
    const int*   lab  = (const int*)d_in[5];
    const float* temp = (const float*)d_in[6];
    float* out = (float*)d_out;

    char* ws = (char*)d_ws;
    __bf16* bagb    = (__bf16*)(ws);                           // 1 MB
    float*  nbsq    = (float*)(ws + (1u << 20));               // 2 KB
    float*  nr      = (float*)(ws + (1u << 20) + 64 * 1024);   // 64 KB
    float*  pos     = (float*)(ws + (1u << 20) + 128 * 1024);  // 64 KB
    __bf16* cwb     = (__bf16*)(ws + (1u << 20) + 192 * 1024); // 128 KB
    float*  diag    = (float*)(ws + (2u << 20) + 64 * 1024);   // 64 KB
    __bf16* repb    = (__bf16*)(ws + (4u << 20));              // 32 MB
    float*  partial = (float*)(ws + (36u << 20));              // 8 MB

    float* loss = out + 27136;

    kab    <<<512, 512, 0, stream>>>(sent, aug, rel, lab, repb, nr, pos,
                                     clsw, cwb, bagb, nbsq, loss);
    k4_gemm<<<520, 512, 0, stream>>>(repb, bagb, nr, nbsq, temp, partial, diag,
                                     cwb, clsb, out);
    k5_neg <<<256, 256, 0, stream>>>(partial, diag, pos, temp, loss);
}

// Round 4
// 193.561 us; speedup vs baseline: 1.0994x; 1.0061x over previous
//
#include <hip/hip_runtime.h>
#include <hip/hip_bf16.h>

// Shapes: B=512, BAG=32, H=1024, C=53.  EPS=1e-8, scale=sqrt(1024)=32.
// Out: bag_out (512*53=27136) f32, then cl_loss scalar -> 27137 floats.

typedef __bf16 bf16x8 __attribute__((ext_vector_type(8)));
typedef __bf16 bf16x4 __attribute__((ext_vector_type(4)));
typedef __bf16 bf16x2 __attribute__((ext_vector_type(2)));
typedef float  f32x4  __attribute__((ext_vector_type(4)));

__device__ inline float wsum(float v) {
    #pragma unroll
    for (int off = 32; off > 0; off >>= 1) v += __shfl_xor(v, off, 64);
    return v;
}

__device__ inline void gll16(const void* g, void* l) {
    __builtin_amdgcn_global_load_lds((const __attribute__((address_space(1))) void*)g,
                                     (__attribute__((address_space(3))) void*)l, 16, 0, 0);
}

__device__ inline f32x4 ntld(const float* p) {
    return __builtin_nontemporal_load((const f32x4*)p);
}

// ---- kab: merged streaming pass + per-bag softmax/bag (one bag per block) ----
// 8 waves x 4 rows = 32 rows/bag. rep rows held in 64KB LDS (bf16) so the bag
// accumulation needs no global re-read.
__global__ __launch_bounds__(512, 4) void kab(
    const float* __restrict__ sent, const float* __restrict__ aug,
    const float* __restrict__ rel_table, const int* __restrict__ labels,
    __bf16* __restrict__ repb, float* __restrict__ nr, float* __restrict__ pos_sim,
    const float* __restrict__ clsw, __bf16* __restrict__ cwb,
    __bf16* __restrict__ bagb, float* __restrict__ nbsq, float* __restrict__ loss)
{
    __shared__ __align__(16) __bf16 repS[32][1024];    // 64 KB
    __shared__ float scoreS[32], alphaS[32], redS[8];
    const int b = blockIdx.x, t = threadIdx.x;
    const int w = t >> 6, lane = t & 63;

    // folded k0: blocks 0..127 convert cls_w (padded to 64 rows); block 0 zeroes loss
    if (b < 128) {
        const int i = b * 512 + t;
        cwb[i] = (i < 53 * 1024) ? (__bf16)clsw[i] : (__bf16)0.0f;
        if (b == 0 && t == 0) *loss = 0.0f;
    }

    const float* relp = rel_table + (size_t)labels[b] * 1024;
    #pragma unroll
    for (int rr = 0; rr < 4; rr++) {
        const int j = w * 4 + rr;                      // row within bag
        const size_t rbase = ((size_t)b * 32 + j) * 1024;
        const float* srow = sent + rbase;
        const float* arow = aug + rbase;
        float P = 0.f, R = 0.f, A = 0.f, D = 0.f;
        #pragma unroll
        for (int i = 0; i < 4; i++) {
            const int h = i * 256 + lane * 4;
            f32x4 v  = ntld(srow + h);                 // nt: read-once
            f32x4 a  = ntld(arow + h);
            f32x4 rl = *(const f32x4*)(relp + h);      // L1-hot across rows
            P += v.x * rl.x + v.y * rl.y + v.z * rl.z + v.w * rl.w;
            R += v.x * v.x + v.y * v.y + v.z * v.z + v.w * v.w;
            A += a.x * a.x + a.y * a.y + a.z * a.z + a.w * a.w;
            D += v.x * a.x + v.y * a.y + v.z * a.z + v.w * a.w;
            bf16x4 vb = { (__bf16)v.x, (__bf16)v.y, (__bf16)v.z, (__bf16)v.w };
            *(bf16x4*)(&repS[j][h]) = vb;
            *(bf16x4*)(repb + rbase + h) = vb;
        }
        #pragma unroll
        for (int off = 32; off > 0; off >>= 1) {
            P += __shfl_xor(P, off, 64);
            R += __shfl_xor(R, off, 64);
            A += __shfl_xor(A, off, 64);
            D += __shfl_xor(D, off, 64);
        }
        if (lane == 0) {
            scoreS[j] = P * (1.0f / 32.0f);            // /sqrt(H)
            float nrv = sqrtf(R), nav = sqrtf(A);
            nr[b * 32 + j] = nrv;
            pos_sim[b * 32 + j] = D / fmaxf(nrv * nav, 1e-8f);
        }
    }
    __syncthreads();

    if (t < 32) {
        float sj = scoreS[t], mx = sj;
        #pragma unroll
        for (int off = 16; off > 0; off >>= 1) mx = fmaxf(mx, __shfl_xor(mx, off, 32));
        float e = __expf(sj - mx), sm = e;
        #pragma unroll
        for (int off = 16; off > 0; off >>= 1) sm += __shfl_xor(sm, off, 32);
        alphaS[t] = e / sm;
    }
    __syncthreads();

    // bag: thread t owns H positions {2t, 2t+1}; LDS reads 2-way bank = free
    float b0 = 0.f, b1 = 0.f;
    #pragma unroll 8
    for (int j = 0; j < 32; j++) {
        const float al = alphaS[j];
        bf16x2 v = *(const bf16x2*)(&repS[j][t * 2]);
        b0 += al * (float)v.x;
        b1 += al * (float)v.y;
    }
    bf16x2 bb = { (__bf16)b0, (__bf16)b1 };
    *(bf16x2*)(bagb + (size_t)b * 1024 + t * 2) = bb;

    float q = b0 * b0 + b1 * b1;
    q = wsum(q);
    if (lane == 0) redS[w] = q;
    __syncthreads();
    if (t == 0)
        nbsq[b] = redS[0] + redS[1] + redS[2] + redS[3]
                + redS[4] + redS[5] + redS[6] + redS[7];
}

// ---- k4: MFMA 128x128 tile, BK=32, 4-buffer depth-2 counted-vmcnt pipeline ----
// 512 threads / 8 waves (wave = 64x32 sub-tile). Buffers: 4 x 16KB, step s uses
// buf (s&3) at smem + ((s&3)<<14). Schedule: stage s+3 while computing s,
// FENCE(4) keeps the TWO newest steps (4 loads) in flight across each barrier
// -> ~2 compute phases of latency cover (was 1 with the 3-buffer version).
// Staging into buf (s+3)&3 == (s-1)&3 is safe: CMP(s-1) finished before the
// last barrier. negp (32KB) overlays bufs 2+3; bufs 2/3 are last read at steps
// 30/31, and a __syncthreads() after CMP(31) precedes any negp write.
// Swizzle: slot (row,kg') holds cols 8*(kg'^rho(row)), rho=(row>>1)&3; staging
// source is pre-swizzled per-lane (coalescing kept: 4 lanes cover one 64B seg);
// fragment reads are conflict-free per 16-lane phase.
__global__ __launch_bounds__(512, 4) void k4_gemm(
    const __bf16* __restrict__ repb, const __bf16* __restrict__ bagb,
    const float* __restrict__ nr, const float* __restrict__ nbsq,
    const float* __restrict__ temp, float* __restrict__ partial, float* __restrict__ diag,
    const __bf16* __restrict__ cwb, const float* __restrict__ bias, float* __restrict__ out)
{
    __shared__ __align__(16) char smem[65536];
    const int bid = blockIdx.x;
    const int t = threadIdx.x, lane = t & 63, w = t >> 6;
    const int m = lane & 15, quad = lane >> 4;

    if (bid >= 512) {
        // ---- folded k3m: bag_out = bagb @ cwb^T + cls_b (t<256 active) ----
        __bf16* Al = (__bf16*)smem;
        __bf16* Bl = (__bf16*)(smem + 8192);
        const int r0 = (bid - 512) * 64;
        f32x4 acc[4] = {};
        const int i0 = (t & 255) * 8;
        const int row0 = i0 >> 5, kk0 = i0 & 31;
        const __bf16* gA = bagb + (size_t)(r0 + row0) * 1024 + kk0;
        const __bf16* gB = cwb + (size_t)row0 * 1024 + kk0;
        const bool act = (t < 256);
        for (int k0 = 0; k0 < 1024; k0 += 64) {
            __syncthreads();
            if (act) {
                gll16(gA + k0,      Al + i0);
                gll16(gA + k0 + 32, Al + 2048 + i0);
                gll16(gB + k0,      Bl + i0);
                gll16(gB + k0 + 32, Bl + 2048 + i0);
            }
            __syncthreads();
            if (act) {
                #pragma unroll
                for (int ks = 0; ks < 2; ks++) {
                    bf16x8 a = *(const bf16x8*)(&Al[ks * 2048 + (w * 16 + m) * 32 + quad * 8]);
                    #pragma unroll
                    for (int n = 0; n < 4; n++) {
                        bf16x8 bf = *(const bf16x8*)(&Bl[ks * 2048 + (n * 16 + m) * 32 + quad * 8]);
                        acc[n] = __builtin_amdgcn_mfma_f32_16x16x32_bf16(a, bf, acc[n], 0, 0, 0);
                    }
                }
            }
        }
        if (act) {
            #pragma unroll
            for (int n = 0; n < 4; n++) {
                const int c = n * 16 + m;
                if (c < 53) {
                    #pragma unroll
                    for (int i = 0; i < 4; i++) {
                        const int r = r0 + w * 16 + quad * 4 + i;
                        out[(size_t)r * 53 + c] = acc[n][i] + bias[c];
                    }
                }
            }
        }
        return;
    }

    float (*negp)[32][128] = (float (*)[32][128])(smem + 32768);  // overlays bufs 2+3

    const int xcd = bid & 7, slot = bid >> 3;
    const int cb = slot & 3, rb = (slot >> 2) * 8 + xcd;
    const int r0 = rb * 128, c0 = cb * 128;
    const int wr0 = (w & 1) * 64, wc0 = (w >> 1) * 32;
    const int half = w & 1;

    // staging: threads 0..255 -> A slots {tt, tt+256}; 256..511 -> B ditto
    const int tt = t & 255;
    const bool isB = (t >= 256);
    const int srow = tt >> 2;                          // 0..63
    const int scol = 8 * ((tt & 3) ^ ((srow >> 1) & 3));
    const __bf16* g0 = (isB ? bagb + (size_t)(c0 + srow) * 1024
                            : repb + (size_t)(r0 + srow) * 1024) + scol;
    const __bf16* g1 = g0 + 64 * 1024;                 // row + 64 (same swizzle)
    const int d0 = (isB ? 4096 : 0) + tt * 8;
    const int d1 = d0 + 2048;

    // fragment-read offsets (bf16 units)
    const int rho = (m >> 1) & 3;
    const int offA = ((wr0 + m) * 4 + (quad ^ rho)) * 8;
    const int offB = 4096 + ((wc0 + m) * 4 + (quad ^ rho)) * 8;

    f32x4 acc[4][2] = {};

    #define BUFB(s) ((__bf16*)(smem + (((s) & 3) << 14)))
    #define STG(s) do { const int kk_ = (s) * 32; __bf16* b_ = BUFB(s);     \
        gll16(g0 + kk_, b_ + d0); gll16(g1 + kk_, b_ + d1); } while (0)

    #define CMP(s) do { const __bf16* b_ = BUFB(s); bf16x8 av_[4], bv_[2];  \
        _Pragma("unroll") for (int i_ = 0; i_ < 4; i_++)                    \
            av_[i_] = *(const bf16x8*)(b_ + offA + i_ * 512);               \
        _Pragma("unroll") for (int n_ = 0; n_ < 2; n_++)                    \
            bv_[n_] = *(const bf16x8*)(b_ + offB + n_ * 512);               \
        _Pragma("unroll") for (int i_ = 0; i_ < 4; i_++)                    \
        _Pragma("unroll") for (int n_ = 0; n_ < 2; n_++)                    \
            acc[i_][n_] = __builtin_amdgcn_mfma_f32_16x16x32_bf16(          \
                av_[i_], bv_[n_], acc[i_][n_], 0, 0, 0); } while (0)

    #define FENCE(N) do { __builtin_amdgcn_sched_barrier(0);                \
        asm volatile("s_waitcnt vmcnt(" #N ")" ::: "memory");               \
        __builtin_amdgcn_s_barrier();                                       \
        __builtin_amdgcn_sched_barrier(0); } while (0)

    STG(0); STG(1); STG(2);
    FENCE(4);                                   // step 0 resident; 1,2 in flight
    #pragma unroll 1
    for (int s = 0; s < 29; ++s) {              // stage s+3, compute s
        STG(s + 3);
        CMP(s);
        FENCE(4);                               // retire s+1; keep s+2,s+3 flying
    }
    CMP(29); FENCE(2);                          // retire step 30
    CMP(30); FENCE(0);                          // retire step 31
    CMP(31);
    __syncthreads();                            // all reads of bufs 2/3 done -> negp safe

    const float invT = 1.0f / *temp;
    float nrv[16];
    #pragma unroll
    for (int i = 0; i < 4; i++)
        #pragma unroll
        for (int g = 0; g < 4; g++)
            nrv[i * 4 + g] = nr[r0 + wr0 + i * 16 + quad * 4 + g];

    #pragma unroll
    for (int n = 0; n < 2; n++) {
        const int c_local = wc0 + n * 16 + m;
        const int cg = c0 + c_local;
        const float nbv = sqrtf(nbsq[cg]);
        #pragma unroll
        for (int i = 0; i < 2; i++) {                  // parity pairs (i, i+2)
            #pragma unroll
            for (int g = 0; g < 4; g++) {
                const int jj = i * 16 + quad * 4 + g;
                const int rg0 = r0 + wr0 + i * 16 + quad * 4 + g;
                const int rg2 = rg0 + 32;
                float e0 = __expf(acc[i][n][g]     / fmaxf(nbv * nrv[i * 4 + g],       1e-8f) * invT);
                float e2 = __expf(acc[i + 2][n][g] / fmaxf(nbv * nrv[(i + 2) * 4 + g], 1e-8f) * invT);
                negp[half][jj][c_local] = e0 + e2;
                if ((rg0 >> 5) == cg) diag[(size_t)cg * 32 + jj] = e0;
                if ((rg2 >> 5) == cg) diag[(size_t)cg * 32 + jj] = e2;
            }
        }
    }
    __syncthreads();

    float* pout = partial + (size_t)rb * 32 * 512 + c0;
    #pragma unroll
    for (int v = 0; v < 2; v++) {
        const int idx = v * 2048 + t * 4;              // 0..4095
        const int jj = idx >> 7, cl = idx & 127;
        f32x4 a = *(const f32x4*)(&negp[0][jj][cl]);
        f32x4 bq = *(const f32x4*)(&negp[1][jj][cl]);
        f32x4 s = a + bq;
        *(f32x4*)(pout + (size_t)jj * 512 + cl) = s;
    }
    #undef BUFB
    #undef STG
    #undef CMP
    #undef FENCE
}

// ---- k5: reduce partial over rb (128) + loss terms; atomic accumulate into loss ----
__global__ __launch_bounds__(256) void k5_neg(
    const float* __restrict__ partial, const float* __restrict__ diag,
    const float* __restrict__ pos_sim, const float* __restrict__ temp,
    float* __restrict__ loss)
{
    const int ct = blockIdx.x & 7, j = blockIdx.x >> 3;
    const int t = threadIdx.x, lane = t & 63, w = t >> 6;
    const int bsub = t >> 4;                           // 0..15 (rb-group of 8)
    const int cidx = t & 15;                           // x4 cols
    f32x4 acc = {};
    #pragma unroll 4
    for (int r = 0; r < 8; r++) {
        const int rb = bsub * 8 + r;
        f32x4 v = *(const f32x4*)(partial + ((size_t)rb * 32 + j) * 512 + ct * 64 + cidx * 4);
        acc += v;
    }
    #pragma unroll
    for (int k = 0; k < 4; k++) {
        acc[k] += __shfl_xor(acc[k], 16, 64);
        acc[k] += __shfl_xor(acc[k], 32, 64);
    }
    __shared__ float red[4][64];
    if (lane < 16) {
        #pragma unroll
        for (int k = 0; k < 4; k++) red[w][lane * 4 + k] = acc[k];
    }
    __syncthreads();

    if (t < 64) {
        const int c = ct * 64 + t;
        float S = red[0][t] + red[1][t] + red[2][t] + red[3][t];
        S -= diag[(size_t)c * 32 + j];                 // near-exact cancellation (f32)
        const float invT = 1.0f / *temp;
        const float lp = pos_sim[(c << 5) + j] * invT;
        float term = logf(__expf(lp) + S) - lp;
        term = wsum(term);
        if (t == 0) atomicAdd(loss, term * (1.0f / 16384.0f));
    }
}

extern "C" void kernel_launch(void* const* d_in, const int* in_sizes, int n_in,
                              void* d_out, int out_size, void* d_ws, size_t ws_size,
                              hipStream_t stream)
{
    const float* sent = (const float*)d_in[0];
    const float* aug  = (const float*)d_in[1];
    const float* rel  = (const float*)d_in[2];
    const float* clsw = (const float*)d_in[3];
    const float* clsb = (const float*)d_in[4];
    const int*   lab  = (const int*)d_in[5];
    const float* temp = (const float*)d_in[6];
    float* out = (float*)d_out;

    char* ws = (char*)d_ws;
    __bf16* bagb    = (__bf16*)(ws);                           // 1 MB
    float*  nbsq    = (float*)(ws + (1u << 20));               // 2 KB
    float*  nr      = (float*)(ws + (1u << 20) + 64 * 1024);   // 64 KB
    float*  pos     = (float*)(ws + (1u << 20) + 128 * 1024);  // 64 KB
    __bf16* cwb     = (__bf16*)(ws + (1u << 20) + 192 * 1024); // 128 KB
    float*  diag    = (float*)(ws + (2u << 20) + 64 * 1024);   // 64 KB
    __bf16* repb    = (__bf16*)(ws + (4u << 20));              // 32 MB
    float*  partial = (float*)(ws + (36u << 20));              // 8 MB

    float* loss = out + 27136;

    kab    <<<512, 512, 0, stream>>>(sent, aug, rel, lab, repb, nr, pos,
                                     clsw, cwb, bagb, nbsq, loss);
    k4_gemm<<<520, 512, 0, stream>>>(repb, bagb, nr, nbsq, temp, partial, diag,
                                     cwb, clsb, out);
    k5_neg <<<256, 256, 0, stream>>>(partial, diag, pos, temp, loss);
}